// Round 1
// baseline (690.884 us; speedup 1.0000x reference)
//
#include <hip/hip_runtime.h>
#include <cmath>

#define D 128
#define TILE 64
#define NT 4  // 4x4 outputs per thread (TILE/16)

// ---------------------------------------------------------------------------
// Kernel 1: row squared-norms for both inputs.
// 16 threads per row, 2 float4 loads each, shfl-tree reduce over width 16.
// norms[0..N)   = |x1 rows|^2
// norms[N..2N)  = |x2 rows|^2
// ---------------------------------------------------------------------------
__global__ __launch_bounds__(256) void row_norms_kernel(
    const float* __restrict__ x1, const float* __restrict__ x2,
    float* __restrict__ norms, int N) {
    int tid = threadIdx.x;
    int r = blockIdx.x * 16 + (tid >> 4);
    if (r >= 2 * N) return;
    int lane16 = tid & 15;
    const float* row = (r < N) ? (x1 + (size_t)r * D) : (x2 + (size_t)(r - N) * D);
    const float4* row4 = (const float4*)row;
    float p = 0.f;
#pragma unroll
    for (int q = 0; q < 2; ++q) {
        float4 v = row4[lane16 * 2 + q];
        p = fmaf(v.x, v.x, p);
        p = fmaf(v.y, v.y, p);
        p = fmaf(v.z, v.z, p);
        p = fmaf(v.w, v.w, p);
    }
#pragma unroll
    for (int off = 8; off; off >>= 1) p += __shfl_down(p, off, 16);
    if (lane16 == 0) norms[r] = p;
}

// ---------------------------------------------------------------------------
// Kernel 2: fused tile GEMM + exp + sum.
// blockIdx.z = job: 0 -> (x1,x1), 1 -> (x2,x2), 2 -> (x1,x2).
// Jobs 0/1 are symmetric: only bi<=bj tiles run; off-diagonal weight = 2.
// 64x64 tile, K=128 fully staged in LDS (exactly 64 KiB static).
// LDS layout: row-major, float4 index XOR-swizzled by (row&31):
//   - global loads perfectly coalesced (consecutive lanes -> consecutive 16B)
//   - LDS writes 4-way conflict (~free), reads <=2-way (free per m136)
// Each thread: rows ty+16i, cols tx+16j (placement is free; we only sum).
// Accumulate exp() in DOUBLE: final answer is sqrt of a ~1e-4 difference of
// ~0.61 means -> each 67M-term mean needs ~1e-6 abs accuracy.
// ---------------------------------------------------------------------------
__global__ __launch_bounds__(256) void mmd_tile_kernel(
    const float* __restrict__ x1, const float* __restrict__ x2,
    const float* __restrict__ norms, double* __restrict__ acc,
    float gamma, int N) {
    __shared__ float4 smem[4096];  // [0,2048): A tile, [2048,4096): B tile

    int job = blockIdx.z;
    int bi = blockIdx.y, bj = blockIdx.x;
    bool sym = (job < 2);
    if (sym && bj < bi) return;

    const float *A, *B, *nA, *nB;
    if (job == 0)      { A = x1; B = x1; nA = norms;     nB = norms;     }
    else if (job == 1) { A = x2; B = x2; nA = norms + N; nB = norms + N; }
    else               { A = x1; B = x2; nA = norms;     nB = norms + N; }
    double weight = (sym && bj > bi) ? 2.0 : 1.0;

    int tid = threadIdx.x;
    float4* As = smem;
    float4* Bs = smem + 2048;
    const float4* Ag = (const float4*)(A + (size_t)bi * TILE * D);
    const float4* Bg = (const float4*)(B + (size_t)bj * TILE * D);

#pragma unroll
    for (int i = 0; i < 8; ++i) {
        int c = tid + i * 256;     // 0..2047 (64 rows x 32 float4)
        int row = c >> 5;
        int kc = c & 31;
        int sw = kc ^ (row & 31);
        As[row * 32 + sw] = Ag[c];
        Bs[row * 32 + sw] = Bg[c];
    }
    __syncthreads();

    int tx = tid & 15, ty = tid >> 4;
    float accr[NT][NT];
#pragma unroll
    for (int i = 0; i < NT; ++i)
#pragma unroll
        for (int j = 0; j < NT; ++j) accr[i][j] = 0.f;

#pragma unroll 4
    for (int kc = 0; kc < 32; ++kc) {
        float4 a[NT], b[NT];
#pragma unroll
        for (int i = 0; i < NT; ++i) {
            int row = ty + 16 * i;
            a[i] = As[row * 32 + (kc ^ (row & 31))];
        }
#pragma unroll
        for (int j = 0; j < NT; ++j) {
            int col = tx + 16 * j;
            b[j] = Bs[col * 32 + (kc ^ (col & 31))];
        }
#pragma unroll
        for (int i = 0; i < NT; ++i)
#pragma unroll
            for (int j = 0; j < NT; ++j) {
                accr[i][j] = fmaf(a[i].x, b[j].x, accr[i][j]);
                accr[i][j] = fmaf(a[i].y, b[j].y, accr[i][j]);
                accr[i][j] = fmaf(a[i].z, b[j].z, accr[i][j]);
                accr[i][j] = fmaf(a[i].w, b[j].w, accr[i][j]);
            }
    }

    // Epilogue: sq -> exp -> double accumulate
    double lsum = 0.0;
    int rB = bi * TILE, cB = bj * TILE;
#pragma unroll
    for (int i = 0; i < NT; ++i) {
        float nr = nA[rB + ty + 16 * i];
#pragma unroll
        for (int j = 0; j < NT; ++j) {
            float nc = nB[cB + tx + 16 * j];
            float sq = fmaxf(nr + nc - 2.f * accr[i][j], 0.f);
            lsum += (double)__expf(-gamma * sq);
        }
    }
    lsum *= weight;

    // wave (64) reduce in double
#pragma unroll
    for (int off = 32; off; off >>= 1) lsum += __shfl_down(lsum, off);

    __syncthreads();  // all LDS reads done before reuse as reduction scratch
    double* red = (double*)smem;
    if ((tid & 63) == 0) red[tid >> 6] = lsum;
    __syncthreads();
    if (tid == 0) {
        double t = red[0] + red[1] + red[2] + red[3];
        // spread atomics over 64 slots per job to avoid same-address serialization
        atomicAdd(&acc[job * 64 + (bi & 63)], t);
    }
}

// ---------------------------------------------------------------------------
// Kernel 3: finalize. acc has 3 jobs x 64 slots of doubles.
// out = sqrt((S11 + S22 - 2*S12) / N^2)
// ---------------------------------------------------------------------------
__global__ __launch_bounds__(64) void mmd_finalize_kernel(
    const double* __restrict__ acc, float* __restrict__ out, int N) {
    int l = threadIdx.x;
    double v = acc[l] + acc[64 + l] - 2.0 * acc[128 + l];
#pragma unroll
    for (int off = 32; off; off >>= 1) v += __shfl_down(v, off);
    if (l == 0) {
        double nn = (double)N * (double)N;
        double s = v / nn;
        out[0] = (float)sqrt(s > 0.0 ? s : 0.0);
    }
}

extern "C" void kernel_launch(void* const* d_in, const int* in_sizes, int n_in,
                              void* d_out, int out_size, void* d_ws, size_t ws_size,
                              hipStream_t stream) {
    const float* x1 = (const float*)d_in[0];
    const float* x2 = (const float*)d_in[1];
    int N = in_sizes[0] / D;  // 8192

    // workspace layout: [0,1536) = 192 double accumulators (3 jobs x 64 slots),
    //                   [2048, 2048+8*N) = 2N float row norms
    double* acc = (double*)d_ws;
    float* norms = (float*)((char*)d_ws + 2048);
    hipMemsetAsync(d_ws, 0, 2048, stream);

    // bandwidth -> gamma (same for both inputs, d = 128), computed on host
    double lg = lgamma(0.5 * (D + 1)) - lgamma(0.5 * D);
    double gz = 2.0 * exp(lg);
    float gamma = (float)(1.0 / (2.0 * gz * gz));

    int nrow_blocks = (2 * N + 15) / 16;
    row_norms_kernel<<<nrow_blocks, 256, 0, stream>>>(x1, x2, norms, N);

    int nt = N / TILE;  // 128
    dim3 grid(nt, nt, 3);
    mmd_tile_kernel<<<grid, 256, 0, stream>>>(x1, x2, norms, acc, gamma, N);

    mmd_finalize_kernel<<<1, 64, 0, stream>>>(acc, (float*)d_out, N);
}

// Round 2
// 176.349 us; speedup vs baseline: 3.9177x; 3.9177x over previous
//
#include <hip/hip_runtime.h>
#include <cmath>

#define D 128
#define BM 128   // block tile (rows and cols)
#define BK 64    // k-chunk staged in LDS

typedef __attribute__((ext_vector_type(8))) short bf16x8;
typedef __attribute__((ext_vector_type(4))) float f32x4;

// round-to-nearest-even fp32 -> bf16 (as ushort)
__device__ __forceinline__ unsigned short f2bf(float f) {
    unsigned u = __float_as_uint(f);
    u += 0x7FFFu + ((u >> 16) & 1u);
    return (unsigned short)(u >> 16);
}
__device__ __forceinline__ float bf2f(unsigned short h) {
    return __uint_as_float(((unsigned)h) << 16);
}

// async global->LDS 16B copy (global_load_lds_dwordx4); LDS dst is
// lane-contiguous (wave-uniform base + lane*16) -- swizzle lives in gsrc.
__device__ __forceinline__ void async_cp16(const void* g, void* l) {
    __builtin_amdgcn_global_load_lds(
        (__attribute__((address_space(1))) void*)g,
        (__attribute__((address_space(3))) void*)l, 16, 0, 0);
}

// ---------------------------------------------------------------------------
// Prep: fp32 x -> bf16 hi/lo split (row-major, x1 rows then x2 rows) +
// per-row E[r] = exp(-gamma * |row|^2).  16 threads/row, 8 elems each.
// ---------------------------------------------------------------------------
__global__ __launch_bounds__(256) void prep_kernel(
    const float* __restrict__ x1, const float* __restrict__ x2,
    unsigned short* __restrict__ hi, unsigned short* __restrict__ lo,
    float* __restrict__ E, float gamma, int N) {
    int tid = threadIdx.x;
    int r = blockIdx.x * 16 + (tid >> 4);
    if (r >= 2 * N) return;
    int l = tid & 15;
    const float* row = (r < N) ? x1 + (size_t)r * D : x2 + (size_t)(r - N) * D;
    float4 v0 = ((const float4*)row)[l * 2];
    float4 v1 = ((const float4*)row)[l * 2 + 1];
    float v[8] = {v0.x, v0.y, v0.z, v0.w, v1.x, v1.y, v1.z, v1.w};
    float p = 0.f;
    unsigned short h[8], lw[8];
#pragma unroll
    for (int j = 0; j < 8; ++j) {
        p = fmaf(v[j], v[j], p);
        h[j] = f2bf(v[j]);
        lw[j] = f2bf(v[j] - bf2f(h[j]));
    }
    size_t base = (size_t)r * D + l * 8;   // ushort index, 16B aligned
    uint4 hp, lp;
    hp.x = h[0] | ((unsigned)h[1] << 16);  hp.y = h[2] | ((unsigned)h[3] << 16);
    hp.z = h[4] | ((unsigned)h[5] << 16);  hp.w = h[6] | ((unsigned)h[7] << 16);
    lp.x = lw[0] | ((unsigned)lw[1] << 16); lp.y = lw[2] | ((unsigned)lw[3] << 16);
    lp.z = lw[4] | ((unsigned)lw[5] << 16); lp.w = lw[6] | ((unsigned)lw[7] << 16);
    *(uint4*)(hi + base) = hp;
    *(uint4*)(lo + base) = lp;
#pragma unroll
    for (int off = 8; off; off >>= 1) p += __shfl_down(p, off, 16);
    if (l == 0) E[r] = expf(-gamma * p);
}

// ---------------------------------------------------------------------------
// Main: fused split-bf16 MFMA GEMM + exp + sum.
// job 0: (x1,x1) sym, 1: (x2,x2) sym, 2: (x1,x2).
// 128x128 tile, K=128 in 2 chunks of 64. LDS 64KB: A_hi|A_lo|B_hi|B_lo,
// each 128 rows x 8 float4, float4-index XOR-swizzled by (row&7).
// dot = AhiBhi + AhiBlo + AloBhi (3 accumulating MFMAs, 16x16x32 bf16).
// Entry = E[row]*E[col]*exp(2*gamma*dot); fp32 per-thread sum -> double.
// ---------------------------------------------------------------------------
__global__ __launch_bounds__(256) void mmd_mfma_kernel(
    const unsigned short* __restrict__ hi, const unsigned short* __restrict__ lo,
    const float* __restrict__ E, double* __restrict__ acc,
    float c2, int N) {
    __shared__ float4 smem[4096];  // 64 KiB

    int job = blockIdx.z;
    int bi = blockIdx.y, bj = blockIdx.x;
    bool sym = (job < 2);
    if (sym && bj < bi) return;
    int aBase = (job == 1 ? N : 0) + bi * BM;  // row block in combined arrays
    int bBase = (job == 0 ? 0 : N) + bj * BM;
    double weight = (sym && bj > bi) ? 2.0 : 1.0;

    int tid = threadIdx.x;
    int lane = tid & 63, wave = tid >> 6;
    int quad = lane >> 4, l16 = lane & 15;
    int wrow = (wave & 1) * 64, wcol = (wave >> 1) * 64;

    f32x4 C[4][4];
#pragma unroll
    for (int i = 0; i < 4; ++i)
#pragma unroll
        for (int j = 0; j < 4; ++j) C[i][j] = {0.f, 0.f, 0.f, 0.f};

    for (int c = 0; c < 2; ++c) {
        if (c) __syncthreads();  // LDS reads of chunk 0 done before overwrite
        // stage 4 regions x 16KB; slot->global inverse of the XOR swizzle
#pragma unroll
        for (int r = 0; r < 4; ++r) {
            const unsigned short* src = (r & 1) ? lo : hi;
            int rowBase = (r < 2) ? aBase : bBase;
#pragma unroll
            for (int i = 0; i < 4; ++i) {
                int slot = i * 256 + tid;        // 0..1023
                int row = slot >> 3, sw = slot & 7;
                int kc4 = sw ^ (row & 7);
                const void* g = src + ((size_t)(rowBase + row) * D + c * BK + kc4 * 8);
                async_cp16(g, &smem[r * 1024 + slot]);
            }
        }
        __syncthreads();
#pragma unroll
        for (int s = 0; s < 2; ++s) {
            int kc4 = s * 4 + quad;
            bf16x8 ah[4], al[4], bh[4], bl[4];
#pragma unroll
            for (int t = 0; t < 4; ++t) {
                int ar = wrow + t * 16 + l16;
                int as = ar * 8 + (kc4 ^ (ar & 7));
                ah[t] = *(const bf16x8*)&smem[as];
                al[t] = *(const bf16x8*)&smem[1024 + as];
                int br = wcol + t * 16 + l16;
                int bs = br * 8 + (kc4 ^ (br & 7));
                bh[t] = *(const bf16x8*)&smem[2048 + bs];
                bl[t] = *(const bf16x8*)&smem[3072 + bs];
            }
#pragma unroll
            for (int ti = 0; ti < 4; ++ti)
#pragma unroll
                for (int tj = 0; tj < 4; ++tj) {
                    C[ti][tj] = __builtin_amdgcn_mfma_f32_16x16x32_bf16(ah[ti], bh[tj], C[ti][tj], 0, 0, 0);
                    C[ti][tj] = __builtin_amdgcn_mfma_f32_16x16x32_bf16(ah[ti], bl[tj], C[ti][tj], 0, 0, 0);
                    C[ti][tj] = __builtin_amdgcn_mfma_f32_16x16x32_bf16(al[ti], bh[tj], C[ti][tj], 0, 0, 0);
                }
        }
    }

    // Epilogue. C/D layout (m89-verified): col = lane&15, row = quad*4 + reg.
    float lsum = 0.f;
    int arow0 = aBase + wrow + quad * 4;
    int bcol0 = bBase + wcol + l16;
#pragma unroll
    for (int ti = 0; ti < 4; ++ti) {
        float4 ea = *(const float4*)&E[arow0 + ti * 16];
#pragma unroll
        for (int tj = 0; tj < 4; ++tj) {
            float eb = E[bcol0 + tj * 16];
            f32x4 d = C[ti][tj];
            float t0 = __expf(c2 * d.x) * ea.x + __expf(c2 * d.y) * ea.y
                     + __expf(c2 * d.z) * ea.z + __expf(c2 * d.w) * ea.w;
            lsum += t0 * eb;
        }
    }
    double ds = (double)lsum * weight;
#pragma unroll
    for (int off = 32; off; off >>= 1) ds += __shfl_down(ds, off);
    __syncthreads();  // LDS reads all done; reuse as reduction scratch
    double* red = (double*)smem;
    if (lane == 0) red[wave] = ds;
    __syncthreads();
    if (tid == 0)
        atomicAdd(&acc[job * 64 + ((bi + bj) & 63)], red[0] + red[1] + red[2] + red[3]);
}

// ---------------------------------------------------------------------------
// Finalize: out = sqrt((S11 + S22 - 2*S12)/N^2)
// ---------------------------------------------------------------------------
__global__ __launch_bounds__(64) void mmd_finalize_kernel(
    const double* __restrict__ acc, float* __restrict__ out, int N) {
    int l = threadIdx.x;
    double v = acc[l] + acc[64 + l] - 2.0 * acc[128 + l];
#pragma unroll
    for (int off = 32; off; off >>= 1) v += __shfl_down(v, off);
    if (l == 0) {
        double nn = (double)N * (double)N;
        double s = v / nn;
        out[0] = (float)sqrt(s > 0.0 ? s : 0.0);
    }
}

extern "C" void kernel_launch(void* const* d_in, const int* in_sizes, int n_in,
                              void* d_out, int out_size, void* d_ws, size_t ws_size,
                              hipStream_t stream) {
    const float* x1 = (const float*)d_in[0];
    const float* x2 = (const float*)d_in[1];
    int N = in_sizes[0] / D;  // 8192

    // ws layout: [0,1536) acc (3 jobs x 64 doubles); E @8192 (2N f32);
    // hi @73728 (2N*128 bf16 = 4MB); lo after (4MB). Total ~8.07 MB.
    double* acc = (double*)d_ws;
    float* E = (float*)((char*)d_ws + 8192);
    unsigned short* hi = (unsigned short*)((char*)d_ws + 73728);
    unsigned short* lo = hi + (size_t)2 * N * D;
    hipMemsetAsync(d_ws, 0, 1536, stream);

    double lg = lgamma(0.5 * (D + 1)) - lgamma(0.5 * D);
    double gz = 2.0 * exp(lg);
    float gamma = (float)(1.0 / (2.0 * gz * gz));
    float c2 = 2.0f * gamma;

    prep_kernel<<<(2 * N + 15) / 16, 256, 0, stream>>>(x1, x2, hi, lo, E, gamma, N);

    int nt = N / BM;  // 64
    dim3 grid(nt, nt, 3);
    mmd_mfma_kernel<<<grid, 256, 0, stream>>>(hi, lo, E, acc, c2, N);

    mmd_finalize_kernel<<<1, 64, 0, stream>>>(acc, (float*)d_out, N);
}

// Round 3
// 116.527 us; speedup vs baseline: 5.9290x; 1.5134x over previous
//
#include <hip/hip_runtime.h>
#include <cmath>

#define D 128
#define BM 128   // block tile (rows and cols)
#define BK 64    // k-chunk staged in LDS

typedef __attribute__((ext_vector_type(8))) _Float16 f16x8;
typedef __attribute__((ext_vector_type(4))) float f32x4;

// async global->LDS 16B copy (global_load_lds_dwordx4); LDS dst is
// lane-contiguous (wave-uniform base + lane*16) -- swizzle lives in gsrc.
__device__ __forceinline__ void async_cp16(const void* g, void* l) {
    __builtin_amdgcn_global_load_lds(
        (__attribute__((address_space(1))) void*)g,
        (__attribute__((address_space(3))) void*)l, 16, 0, 0);
}

// ---------------------------------------------------------------------------
// Prep: fp32 x -> fp16 (RTN), combined array [x1 rows; x2 rows], +
// per-row E[r] = exp(-gamma*|row|^2) in fp32. 16 threads/row, 8 elems each.
// Single-pass fp16 precision: per-element eps ~1.6e-4 rms, zero-mean ->
// dot err ~2.6e-3 -> exp-arg err ~1e-5 -> mean err ~1e-8 << 3.6e-6 budget.
// ---------------------------------------------------------------------------
__global__ __launch_bounds__(256) void prep_kernel(
    const float* __restrict__ x1, const float* __restrict__ x2,
    _Float16* __restrict__ xh, float* __restrict__ E, float gamma, int N) {
    int tid = threadIdx.x;
    int r = blockIdx.x * 16 + (tid >> 4);
    if (r >= 2 * N) return;
    int l = tid & 15;
    const float* row = (r < N) ? x1 + (size_t)r * D : x2 + (size_t)(r - N) * D;
    float4 v0 = ((const float4*)row)[l * 2];
    float4 v1 = ((const float4*)row)[l * 2 + 1];
    float v[8] = {v0.x, v0.y, v0.z, v0.w, v1.x, v1.y, v1.z, v1.w};
    float p = 0.f;
    _Float16 h8[8];
#pragma unroll
    for (int j = 0; j < 8; ++j) {
        p = fmaf(v[j], v[j], p);
        h8[j] = (_Float16)v[j];   // RTN-even
    }
    *(uint4*)(xh + (size_t)r * D + l * 8) = *(uint4*)h8;
#pragma unroll
    for (int off = 8; off; off >>= 1) p += __shfl_down(p, off, 16);
    if (l == 0) E[r] = expf(-gamma * p);
}

// ---------------------------------------------------------------------------
// Main: one triangular pass over the combined (2N)x(2N) Gram matrix.
// Lower-triangle block decode: t -> (bi >= bj), 128x129/2 = 8256 blocks.
// Signed weight folds m11 - 2*m12 + m22 into ONE accumulator:
//   bi==bj: +1; same class off-diag: +2; cross class: -2.
// 128x128 tile, K=128 in 2 chunks of 64. LDS 32 KiB (A|B, 16 KiB each),
// float4-index XOR-swizzled by (row&7) -> 0 bank conflicts (R2-measured).
// 16x16x32 fp16 MFMA, 4x4 frags/wave. Entry = E[i]*E[j]*exp(2*gamma*dot).
// 32 KiB LDS + launch_bounds(256,4) -> 4 blocks/CU (50% occupancy).
// ---------------------------------------------------------------------------
__global__ __launch_bounds__(256, 4) void mmd_mfma_kernel(
    const _Float16* __restrict__ xh, const float* __restrict__ E,
    double* __restrict__ acc, float c2, int N) {
    __shared__ float4 smem[2048];  // 32 KiB: [0,1024) A, [1024,2048) B

    // triangular decode (wave-uniform scalar math)
    int t = blockIdx.x;
    int bi = (int)((sqrtf(8.0f * t + 1.0f) - 1.0f) * 0.5f);
    while ((bi + 1) * (bi + 2) / 2 <= t) ++bi;
    while (bi * (bi + 1) / 2 > t) --bi;
    int bj = t - bi * (bi + 1) / 2;   // bj <= bi

    int half = N / BM;                 // 64: first `half` blocks are x1 rows
    float w = (bi == bj) ? 1.0f : 2.0f;
    if ((bi < half) != (bj < half)) w = -2.0f;
    int aBase = bi * BM, bBase = bj * BM;

    int tid = threadIdx.x;
    int lane = tid & 63, wave = tid >> 6;
    int quad = lane >> 4, l16 = lane & 15;
    int wrow = (wave & 1) * 64, wcol = (wave >> 1) * 64;

    f32x4 C[4][4];
#pragma unroll
    for (int i = 0; i < 4; ++i)
#pragma unroll
        for (int j = 0; j < 4; ++j) C[i][j] = {0.f, 0.f, 0.f, 0.f};

    for (int c = 0; c < 2; ++c) {
        if (c) __syncthreads();  // chunk-0 LDS reads done before overwrite
        // stage A and B tiles: 2 regions x 1024 float4 slots
#pragma unroll
        for (int r = 0; r < 2; ++r) {
            int rowBase = r ? bBase : aBase;
#pragma unroll
            for (int i = 0; i < 4; ++i) {
                int slot = i * 256 + tid;            // 0..1023
                int row = slot >> 3, g = slot & 7;
                int kc4 = g ^ (row & 7);
                const void* gp = xh + ((size_t)(rowBase + row) * D + c * BK + kc4 * 8);
                async_cp16(gp, &smem[r * 1024 + slot]);
            }
        }
        __syncthreads();
#pragma unroll
        for (int s = 0; s < 2; ++s) {
            int kc4 = s * 4 + quad;
            f16x8 a[4], b[4];
#pragma unroll
            for (int u = 0; u < 4; ++u) {
                int ar = wrow + u * 16 + l16;
                a[u] = *(const f16x8*)&smem[ar * 8 + (kc4 ^ (ar & 7))];
                int br = wcol + u * 16 + l16;
                b[u] = *(const f16x8*)&smem[1024 + br * 8 + (kc4 ^ (br & 7))];
            }
#pragma unroll
            for (int ti = 0; ti < 4; ++ti)
#pragma unroll
                for (int tj = 0; tj < 4; ++tj)
                    C[ti][tj] = __builtin_amdgcn_mfma_f32_16x16x32_f16(a[ti], b[tj], C[ti][tj], 0, 0, 0);
        }
    }

    // Epilogue. C/D layout (m89-verified): col = lane&15, row = quad*4 + reg.
    float lsum = 0.f;
    int arow0 = aBase + wrow + quad * 4;
    int bcol0 = bBase + wcol + l16;
#pragma unroll
    for (int ti = 0; ti < 4; ++ti) {
        float4 ea = *(const float4*)&E[arow0 + ti * 16];
#pragma unroll
        for (int tj = 0; tj < 4; ++tj) {
            float eb = E[bcol0 + tj * 16];
            f32x4 d = C[ti][tj];
            float t0 = __expf(c2 * d.x) * ea.x + __expf(c2 * d.y) * ea.y
                     + __expf(c2 * d.z) * ea.z + __expf(c2 * d.w) * ea.w;
            lsum += t0 * eb;
        }
    }
    double ds = (double)lsum * (double)w;
#pragma unroll
    for (int off = 32; off; off >>= 1) ds += __shfl_down(ds, off);
    __syncthreads();  // LDS reads all done; reuse as reduction scratch
    double* red = (double*)smem;
    if (lane == 0) red[wave] = ds;
    __syncthreads();
    if (tid == 0)
        atomicAdd(&acc[(bi + bj) & 63], red[0] + red[1] + red[2] + red[3]);
}

// ---------------------------------------------------------------------------
// Finalize: out = sqrt(max(S/N^2, 0)), S already = S11 + S22 - 2*S12.
// ---------------------------------------------------------------------------
__global__ __launch_bounds__(64) void mmd_finalize_kernel(
    const double* __restrict__ acc, float* __restrict__ out, int N) {
    int l = threadIdx.x;
    double v = acc[l];
#pragma unroll
    for (int off = 32; off; off >>= 1) v += __shfl_down(v, off);
    if (l == 0) {
        double nn = (double)N * (double)N;
        double s = v / nn;
        out[0] = (float)sqrt(s > 0.0 ? s : 0.0);
    }
}

extern "C" void kernel_launch(void* const* d_in, const int* in_sizes, int n_in,
                              void* d_out, int out_size, void* d_ws, size_t ws_size,
                              hipStream_t stream) {
    const float* x1 = (const float*)d_in[0];
    const float* x2 = (const float*)d_in[1];
    int N = in_sizes[0] / D;  // 8192

    // ws layout: [0,512) acc (64 doubles); E @8192 (2N f32 = 64 KB);
    // xh @73728 (2N*128 fp16 = 4 MB). Total ~4.07 MB.
    double* acc = (double*)d_ws;
    float* E = (float*)((char*)d_ws + 8192);
    _Float16* xh = (_Float16*)((char*)d_ws + 73728);
    hipMemsetAsync(d_ws, 0, 512, stream);

    double lg = lgamma(0.5 * (D + 1)) - lgamma(0.5 * D);
    double gz = 2.0 * exp(lg);
    float gamma = (float)(1.0 / (2.0 * gz * gz));
    float c2 = 2.0f * gamma;

    prep_kernel<<<(2 * N + 15) / 16, 256, 0, stream>>>(x1, x2, xh, E, gamma, N);

    int nt2 = 2 * N / BM;                  // 128 combined block-rows
    int nblocks = nt2 * (nt2 + 1) / 2;     // 8256 triangular blocks
    mmd_mfma_kernel<<<nblocks, 256, 0, stream>>>(xh, E, acc, c2, N);

    mmd_finalize_kernel<<<1, 64, 0, stream>>>(acc, (float*)d_out, N);
}